// Round 5
// baseline (282.131 us; speedup 1.0000x reference)
//
#include <hip/hip_runtime.h>
#include <hip/hip_bf16.h>
#include <cstdint>
#include <math.h>

#define BB 2
#define TT 1024
#define DIMM 768
#define NHEADS 8
#define DHH 96
#define MLPD 3072
#define NN 2048   // 2*T

typedef unsigned short u16;
using short8 = __attribute__((ext_vector_type(8))) short;
using f32x4  = __attribute__((ext_vector_type(4))) float;
using f32x16 = __attribute__((ext_vector_type(16))) float;
using int4v  = __attribute__((ext_vector_type(4))) int;
union S8I4 { int4v i; short8 s; };

static constexpr float kEps = 1e-6f;

__device__ __forceinline__ float siluf(float x){ return x / (1.f + expf(-x)); }
__device__ __forceinline__ float geluf(float x){ return 0.5f*x*(1.f + erff(x*0.7071067811865475f)); }
__device__ __forceinline__ float bf16_rne(float x){
  uint32_t u = __float_as_uint(x);
  u = (u + 0x7fffu + ((u >> 16) & 1u)) & 0xffff0000u;
  return __uint_as_float(u);
}
__device__ __forceinline__ u16 f2b(float x){
  uint32_t u = __float_as_uint(x);
  return (u16)((u + 0x7fffu + ((u >> 16) & 1u)) >> 16);
}
__device__ __forceinline__ float b2f(u16 b){
  return __uint_as_float(((uint32_t)b) << 16);
}
__device__ __forceinline__ int cvtpk(float lo, float hi){
  int d; asm("v_cvt_pk_bf16_f32 %0, %1, %2" : "=v"(d) : "v"(lo), "v"(hi)); return d;
}
__device__ __forceinline__ void gload16(const void* g, void* l){
  __builtin_amdgcn_global_load_lds((const __attribute__((address_space(1))) unsigned int*)g,
                                   (__attribute__((address_space(3))) unsigned int*)l, 16, 0, 0);
}

// ---------------- modulation MLP (fp32, tiny) ----------------
__global__ __launch_bounds__(256) void mod_stage1_k(
    const float* __restrict__ p_emb, const float* __restrict__ w1,
    const float* __restrict__ b1, float* __restrict__ h2){
  __shared__ float sp[1024];
  const int b = blockIdx.x >> 1;
  const int obase = (blockIdx.x & 1) * 256;
  for (int i = threadIdx.x; i < 1024; i += 256)
    sp[i] = siluf(p_emb[b*1024 + i]);
  __syncthreads();
  const int o = obase + threadIdx.x;
  float acc = 0.f;
  for (int j = 0; j < 1024; ++j) acc += sp[j] * w1[j*512 + o];
  h2[b*512 + o] = siluf(acc + b1[o]);
}

__global__ __launch_bounds__(256) void mod_stage2_k(
    const float* __restrict__ h2, const float* __restrict__ w2,
    const float* __restrict__ b2, float* __restrict__ mod){
  __shared__ float sh[512];
  const int b = blockIdx.x / 36;
  const int obase = (blockIdx.x % 36) * 256;
  for (int i = threadIdx.x; i < 512; i += 256)
    sh[i] = h2[b*512 + i];
  __syncthreads();
  const int o = obase + threadIdx.x;
  float acc = 0.f;
  for (int j = 0; j < 512; ++j) acc += sh[j] * w2[j*9216 + o];
  mod[b*9216 + o] = acc + b2[o];
}

// ------------- fused weight convert+transpose (all 7 weights, 1 launch) -----
__global__ __launch_bounds__(256) void wt_all_k(
    const float* __restrict__ s0, u16* __restrict__ d0,
    const float* __restrict__ s1, u16* __restrict__ d1,
    const float* __restrict__ s2, u16* __restrict__ d2,
    const float* __restrict__ s3, u16* __restrict__ d3,
    const float* __restrict__ s4, u16* __restrict__ d4,
    const float* __restrict__ s5, u16* __restrict__ d5,
    const float* __restrict__ s6, u16* __restrict__ d6){
  const int bid = blockIdx.x;
  const float* S; u16* D; int K, N, lid;
  if      (bid < 1728) { S=s0; D=d0; K=768;  N=2304; lid=bid; }
  else if (bid < 3456) { S=s1; D=d1; K=768;  N=2304; lid=bid-1728; }
  else if (bid < 4032) { S=s2; D=d2; K=768;  N=768;  lid=bid-3456; }
  else if (bid < 6336) { S=s3; D=d3; K=768;  N=3072; lid=bid-4032; }
  else if (bid < 8640) { S=s4; D=d4; K=3072; N=768;  lid=bid-6336; }
  else if (bid < 10944){ S=s5; D=d5; K=768;  N=3072; lid=bid-8640; }
  else                 { S=s6; D=d6; K=3072; N=768;  lid=bid-10944; }
  const int nx = N >> 5;
  const int k0 = (lid / nx) * 32, n0 = (lid % nx) * 32;
  __shared__ float t[32][33];
  const int tx = threadIdx.x & 31, ty = threadIdx.x >> 5;
  for (int i = ty; i < 32; i += 8)
    t[i][tx] = S[(size_t)(k0+i)*N + n0 + tx];
  __syncthreads();
  for (int i = ty; i < 32; i += 8)
    D[(size_t)(n0+i)*K + k0 + tx] = f2b(t[tx][i]);
}

// ---------------- RMSNorm + modulation -> bf16 (both streams, 1 launch) ----
__global__ __launch_bounds__(256) void rmsnorm2_k(
    const float* __restrict__ x0, const float* __restrict__ w0, int cs0, int ch0, u16* __restrict__ o0,
    const float* __restrict__ x1, const float* __restrict__ w1, int cs1, int ch1, u16* __restrict__ o1,
    const float* __restrict__ mod){
  const int rowg = blockIdx.x;
  const int s = rowg >> 11;
  const int row = rowg & 2047;
  const float* x = s ? x1 : x0;
  const float* w = s ? w1 : w0;
  const int cs = s ? cs1 : cs0, ch = s ? ch1 : ch0;
  u16* out = s ? o1 : o0;
  const int b = row >> 10;
  const int tid = threadIdx.x;
  const float* xr = x + (size_t)row * DIMM;
  float v0 = xr[tid], v1 = xr[tid + 256], v2 = xr[tid + 512];
  float ss = v0*v0 + v1*v1 + v2*v2;
  __shared__ float red[4];
  for (int m = 1; m < 64; m <<= 1) ss += __shfl_xor(ss, m, 64);
  if ((tid & 63) == 0) red[tid >> 6] = ss;
  __syncthreads();
  float tot = red[0] + red[1] + red[2] + red[3];
  float rms = rsqrtf(tot * (1.f/768.f) + kEps);
  const float* ms = mod + (size_t)b*9216 + (size_t)cs*768;
  const float* mh = mod + (size_t)b*9216 + (size_t)ch*768;
  u16* orow = out + (size_t)row * DIMM;
  orow[tid]       = f2b(v0*rms*w[tid]      *(1.f+ms[tid])       + mh[tid]);
  orow[tid + 256] = f2b(v1*rms*w[tid+256]  *(1.f+ms[tid+256])   + mh[tid+256]);
  orow[tid + 512] = f2b(v2*rms*w[tid+512]  *(1.f+ms[tid+512])   + mh[tid+512]);
}

// ------- pipelined 4-wave bf16 MFMA GEMM (QKV, MLP-up): 128x128, BK=32 -----
// Triple-buffered LDS, loads 2 tiles ahead, counted vmcnt, raw s_barrier.
// Per thread per tile: 4 global_load_lds  =>  s_waitcnt vmcnt(4) leaves the
// next tile's loads in flight while guaranteeing the current tile is resident.
// EPI: 1 = bf16 store; 2 = gelu->bf16 store.
template<int EPI, int DUAL>
__global__ __launch_bounds__(256) void gemm_pipe_k(
    const u16* __restrict__ A0, const u16* __restrict__ Bt0,
    const float* __restrict__ bias0, void* __restrict__ C0,
    const u16* __restrict__ A1, const u16* __restrict__ Bt1,
    const float* __restrict__ bias1, void* __restrict__ C1,
    int M, int N, int K){
  __shared__ u16 As[3][128*32];
  __shared__ u16 Bs[3][128*32];
  const int z = DUAL ? blockIdx.z : 0;
  const u16* A      = z ? A1 : A0;
  const u16* Bt     = z ? Bt1 : Bt0;
  const float* bias = z ? bias1 : bias0;
  void* C           = z ? C1 : C0;
  const int tid = threadIdx.x;
  const int w = tid >> 6, l = tid & 63;
  const int m0 = blockIdx.y*128, n0 = blockIdx.x*128;
  const int wr = w >> 1, wc = w & 1;
  const int la = l & 15, hi4 = l >> 4;
  f32x4 acc[4][4] = {};
  const int nk = K >> 5;
  // per-thread staging coords (constant across tiles)
  const int sb0 = w*128, sb1 = w*128 + 64;
  const int r0 = (sb0 + l) >> 2, c0 = ((sb0 + l) & 3) * 8;
  const int r1 = (sb1 + l) >> 2, c1 = ((sb1 + l) & 3) * 8;
  const u16* Ar0 = A  + (size_t)(m0+r0)*K + c0;
  const u16* Ar1 = A  + (size_t)(m0+r1)*K + c1;
  const u16* Br0 = Bt + (size_t)(n0+r0)*K + c0;
  const u16* Br1 = Bt + (size_t)(n0+r1)*K + c1;
  #define STAGE(buf, kofs) { \
    gload16(Ar0 + (kofs), &As[buf][sb0*8]); \
    gload16(Br0 + (kofs), &Bs[buf][sb0*8]); \
    gload16(Ar1 + (kofs), &As[buf][sb1*8]); \
    gload16(Br1 + (kofs), &Bs[buf][sb1*8]); }
  // prologue: stage tiles 0 and 1
  STAGE(0, 0);
  STAGE(1, 32);
  int cur = 0;
  for (int kt = 0; kt < nk; ++kt){
    if (kt + 1 < nk){ asm volatile("s_waitcnt vmcnt(4)" ::: "memory"); }
    else            { asm volatile("s_waitcnt vmcnt(0)" ::: "memory"); }
    __builtin_amdgcn_s_barrier();
    if (kt + 2 < nk){
      int nb = cur + 2; if (nb >= 3) nb -= 3;
      STAGE(nb, (kt+2) << 5);
    }
    short8 af[4], bf[4];
    #pragma unroll
    for (int mi = 0; mi < 4; ++mi)
      af[mi] = *(const short8*)((const char*)&As[cur][0] + (wr*64 + mi*16 + la)*64 + hi4*16);
    #pragma unroll
    for (int ni = 0; ni < 4; ++ni)
      bf[ni] = *(const short8*)((const char*)&Bs[cur][0] + (wc*64 + ni*16 + la)*64 + hi4*16);
    #pragma unroll
    for (int mi = 0; mi < 4; ++mi)
      #pragma unroll
      for (int ni = 0; ni < 4; ++ni)
        acc[mi][ni] = __builtin_amdgcn_mfma_f32_16x16x32_bf16(af[mi], bf[ni], acc[mi][ni], 0, 0, 0);
    if (++cur == 3) cur = 0;
  }
  #undef STAGE
  #pragma unroll
  for (int mi = 0; mi < 4; ++mi){
    #pragma unroll
    for (int ni = 0; ni < 4; ++ni){
      const int n = n0 + wc*64 + ni*16 + la;
      const float bv = bias[n];
      #pragma unroll
      for (int rr = 0; rr < 4; ++rr){
        const int m = m0 + wr*64 + mi*16 + hi4*4 + rr;
        float v = acc[mi][ni][rr] + bv;
        if constexpr (EPI == 2) v = geluf(v);
        ((u16*)C)[(size_t)m*N + n] = f2b(v);
      }
    }
  }
}

// ---------------- 16-wave split-K=4 GEMM (192-block shapes, N=768) ---------
// 1024 threads = 4 K-groups x 4 waves; 128x128 tile; combine via LDS.
// EPI: 3 = O = X + (v)*gate (outproj+residual); 4 = O += v*gate (final add).
template<int EPI, int DUAL>
__global__ __launch_bounds__(1024) void gemm16_k(
    const u16* __restrict__ A0, const u16* __restrict__ Bt0,
    const float* __restrict__ bias0,
    const u16* __restrict__ A1, const u16* __restrict__ Bt1,
    const float* __restrict__ bias1,
    const float* __restrict__ mod, const float* __restrict__ X0,
    const float* __restrict__ X1, float* __restrict__ O0,
    float* __restrict__ O1, int cg0, int cg1,
    int M, int N, int K){
  __shared__ char lds[131072];   // 4 groups x 32KB staging; reused for combine
  const int bid = blockIdx.x;
  const int xcd = bid & 7, kk = bid >> 3;
  const int g = xcd + 8*(kk/6);      // 32 (y,z) panel groups, 6 x-blocks each
  const int x = kk % 6;
  int by, z;
  if constexpr (DUAL){ by = g & 15; z = g >> 4; } else { by = g; z = 0; }
  const u16* A      = z ? A1 : A0;
  const u16* Bt     = z ? Bt1 : Bt0;
  const float* bias = z ? bias1 : bias0;
  const int tid = threadIdx.x;
  const int w = tid >> 6, l = tid & 63;
  const int kg = w >> 2, gw = w & 3;
  const int m0 = by*128, n0 = x*128;
  const int wr = gw >> 1, wc = gw & 1;
  const int la = l & 15, hi4 = l >> 4;
  u16* AsG = (u16*)(lds + kg*32768);
  u16* BsG = (u16*)(lds + kg*32768 + 16384);
  const int Kg = K >> 2;
  const int nk = Kg >> 5;
  const int kbase = kg * Kg;
  f32x4 acc[4][4] = {};
  #pragma unroll
  for (int it = 0; it < 2; ++it){
    const int sb = gw*128 + it*64;
    const int s = sb + l;
    const int row = s >> 2, sl = s & 3;
    gload16(A  + (size_t)(m0+row)*K + kbase + sl*8, AsG + sb*8);
    gload16(Bt + (size_t)(n0+row)*K + kbase + sl*8, BsG + sb*8);
  }
  __syncthreads();
  for (int kt = 0; kt < nk; ++kt){
    const int cur = kt & 1;
    if (kt + 1 < nk){
      const int k0n = kbase + ((kt+1) << 5);
      #pragma unroll
      for (int it = 0; it < 2; ++it){
        const int sb = gw*128 + it*64;
        const int s = sb + l;
        const int row = s >> 2, sl = s & 3;
        gload16(A  + (size_t)(m0+row)*K + k0n + sl*8, AsG + (cur^1)*4096 + sb*8);
        gload16(Bt + (size_t)(n0+row)*K + k0n + sl*8, BsG + (cur^1)*4096 + sb*8);
      }
    }
    short8 af[4], bf[4];
    #pragma unroll
    for (int mi = 0; mi < 4; ++mi)
      af[mi] = *(const short8*)(AsG + cur*4096 + (wr*64 + mi*16 + la)*32 + hi4*8);
    #pragma unroll
    for (int ni = 0; ni < 4; ++ni)
      bf[ni] = *(const short8*)(BsG + cur*4096 + (wc*64 + ni*16 + la)*32 + hi4*8);
    #pragma unroll
    for (int mi = 0; mi < 4; ++mi)
      #pragma unroll
      for (int ni = 0; ni < 4; ++ni)
        acc[mi][ni] = __builtin_amdgcn_mfma_f32_16x16x32_bf16(af[mi], bf[ni], acc[mi][ni], 0, 0, 0);
    __syncthreads();
  }
  // combine the 4 K-group partials through LDS (tree: {1->0, 3->2} then {2->0})
  float* c0 = (float*)lds;
  float* c1 = (float*)(lds + 65536);
  #define WRACC(cb) { \
    _Pragma("unroll") for (int mi = 0; mi < 4; ++mi) \
    _Pragma("unroll") for (int ni = 0; ni < 4; ++ni) \
    _Pragma("unroll") for (int rr = 0; rr < 4; ++rr) \
      (cb)[(wr*64+mi*16+hi4*4+rr)*128 + wc*64+ni*16+la] = acc[mi][ni][rr]; }
  #define RDACC(cb) { \
    _Pragma("unroll") for (int mi = 0; mi < 4; ++mi) \
    _Pragma("unroll") for (int ni = 0; ni < 4; ++ni) \
    _Pragma("unroll") for (int rr = 0; rr < 4; ++rr) \
      acc[mi][ni][rr] += (cb)[(wr*64+mi*16+hi4*4+rr)*128 + wc*64+ni*16+la]; }
  if (kg == 1) WRACC(c0);
  if (kg == 3) WRACC(c1);
  __syncthreads();
  if (kg == 0) RDACC(c0);
  if (kg == 2) RDACC(c1);
  __syncthreads();
  if (kg == 2) WRACC(c0);
  __syncthreads();
  if (kg == 0){
    RDACC(c0);
    #pragma unroll
    for (int mi = 0; mi < 4; ++mi){
      #pragma unroll
      for (int ni = 0; ni < 4; ++ni){
        const int n = n0 + wc*64 + ni*16 + la;
        const float bv = bias[n];
        #pragma unroll
        for (int rr = 0; rr < 4; ++rr){
          const int m = m0 + wr*64 + mi*16 + hi4*4 + rr;
          float v = acc[mi][ni][rr] + bv;
          if constexpr (EPI == 3){
            const int bb = m >> 11, ss = (m >> 10) & 1, t = m & 1023;
            const float* X = ss ? X1 : X0;
            float* O = ss ? O1 : O0;
            const float gmod = mod[(size_t)bb*9216 + (size_t)(ss ? cg1 : cg0)*768 + n];
            const size_t oi = ((size_t)(bb*1024 + t))*768 + n;
            O[oi] = X[oi] + v*gmod;
          } else {
            float* O = z ? O1 : O0;
            const int cg = z ? cg1 : cg0;
            const int bb = m >> 10;
            const float gmod = mod[(size_t)bb*9216 + (size_t)cg*768 + n];
            O[(size_t)m*N + n] += v*gmod;
          }
        }
      }
    }
  }
  #undef WRACC
  #undef RDACC
}

// ---------------- head split + RoPE + L2norm*scale (bf16 io) ---------------
__global__ __launch_bounds__(256) void build_qkv_k(
    const u16* __restrict__ qkv1, const u16* __restrict__ qkv2,
    const float* __restrict__ qk_scale,
    u16* __restrict__ Q, u16* __restrict__ K, u16* __restrict__ V){
  const int wid = threadIdx.x >> 6;
  const int lane = threadIdx.x & 63;
  const int row = blockIdx.x * 4 + wid;         // (b*8+h)*2048 + n
  const int n = row & 2047;
  const int h = (row >> 11) & 7;
  const int b = row >> 14;
  const u16* src = (n < TT) ? (qkv1 + ((size_t)b*TT + n) * 2304)
                            : (qkv2 + ((size_t)b*TT + (n - TT)) * 2304);
  const int col = h * DHH;
  const bool act = lane < 48;
  float q0=0,q1=0,k0=0,k1=0,v0=0,v1=0,c=1.f,s=0.f,sc0=0,sc1=0;
  if (act){
    q0 = b2f(src[col + lane]);        q1 = b2f(src[col + lane + 48]);
    k0 = b2f(src[768 + col + lane]);  k1 = b2f(src[768 + col + lane + 48]);
    v0 = b2f(src[1536 + col + lane]); v1 = b2f(src[1536 + col + lane + 48]);
    float inv = bf16_rne((float)(1.0 / pow(10000.0, (2.0 * lane) / 96.0)));
    float ang = (float)n * inv;
    c = cosf(ang); s = sinf(ang);
    sc0 = qk_scale[lane]; sc1 = qk_scale[lane + 48];
  }
  float qr0 = q0*c - q1*s, qr1 = q1*c + q0*s;
  float kr0 = k0*c - k1*s, kr1 = k1*c + k0*s;
  float ssq = qr0*qr0 + qr1*qr1;
  float ssk = kr0*kr0 + kr1*kr1;
  for (int m = 1; m < 64; m <<= 1){ ssq += __shfl_xor(ssq, m, 64); ssk += __shfl_xor(ssk, m, 64); }
  float rq = 1.f / fmaxf(sqrtf(ssq), 1e-12f);
  float rk = 1.f / fmaxf(sqrtf(ssk), 1e-12f);
  const float sscale = 0.1020620726159658f;  // 96^-0.5 folded into Q
  if (act){
    size_t base = (size_t)row * DHH;
    Q[base + lane]      = f2b(qr0*rq*sc0*sscale);  Q[base + lane + 48] = f2b(qr1*rq*sc1*sscale);
    K[base + lane]      = f2b(kr0*rk*sc0);         K[base + lane + 48] = f2b(kr1*rk*sc1);
    V[base + lane]      = f2b(v0);                 V[base + lane + 48] = f2b(v1);
  }
}

// ---------------- V transpose: Vtmp[bh][n][96] -> Vt[bh][96][2048] ----------
__global__ __launch_bounds__(256) void vtrans_k(
    const u16* __restrict__ Vtmp, u16* __restrict__ Vt){
  __shared__ u16 t[32][33];
  const int bh = blockIdx.z;
  const int n0 = blockIdx.x*32, d0 = blockIdx.y*32;
  const int tx = threadIdx.x & 31, ty = threadIdx.x >> 5;
  for (int i = ty; i < 32; i += 8)
    t[i][tx] = Vtmp[((size_t)bh*NN + n0+i)*DHH + d0 + tx];
  __syncthreads();
  for (int i = ty; i < 32; i += 8)
    Vt[((size_t)bh*DHH + d0+i)*NN + n0 + tx] = t[tx][i];
}

// ---------------- MFMA flash attention, 8 waves = 2 KV-split groups --------
#define CROW(r) (((r)&3) + 8*((r)>>2) + 4*hi)
#define SMAXC 10.5f
#define BUILD_PA(dst, vec, basei) { \
  int a1_ = cvtpk(vec[basei+0], vec[basei+1]); \
  int b1_ = cvtpk(vec[basei+4], vec[basei+5]); \
  asm("v_permlane32_swap_b32 %0, %1" : "+v"(a1_), "+v"(b1_)); \
  int a2_ = cvtpk(vec[basei+2], vec[basei+3]); \
  int b2_ = cvtpk(vec[basei+6], vec[basei+7]); \
  asm("v_permlane32_swap_b32 %0, %1" : "+v"(a2_), "+v"(b2_)); \
  S8I4 u_; u_.i = (int4v){a1_, a2_, b1_, b2_}; dst = u_.s; }

__global__ __launch_bounds__(512) void attn_mfma_k(
    const u16* __restrict__ Qg, const u16* __restrict__ Kg,
    const u16* __restrict__ Vtg, u16* __restrict__ AO){
  __shared__ u16 Ks[2][2][64*128];   // [group][buf]; 64 rows x 256B, XOR-swizzled
  __shared__ u16 Vs[2][2][96*64];    // [group][buf]; 96 rows x 128B, XOR-swizzled
  const int bh = blockIdx.x >> 4;
  const int qblk = blockIdx.x & 15;
  const int b = bh >> 3, h = bh & 7;
  const int tid = threadIdx.x;
  const int w = tid >> 6, l = tid & 63;
  const int g2 = w >> 2, wq = w & 3;
  const int gtid = tid & 255;
  const int hi = l >> 5, li = l & 31;
  const int q0w = qblk*128 + wq*32;
  const int kvbase = g2 * 1024;

  short8 qf[6];
  {
    const u16* qrow = Qg + ((size_t)bh*NN + q0w + li)*DHH;
    #pragma unroll
    for (int ks = 0; ks < 6; ++ks)
      qf[ks] = *(const short8*)(qrow + ks*16 + hi*8);
  }

  f32x16 o0, o1, o2;
  #pragma unroll
  for (int r = 0; r < 16; ++r){ o0[r]=0.f; o1[r]=0.f; o2[r]=0.f; }
  float lrun = 0.f;

  {
    #pragma unroll
    for (int it = 0; it < 3; ++it){
      const int s = gtid + it*256;
      const int krow = s/12, ksl = s%12;
      short8 kv = *(const short8*)(Kg + ((size_t)bh*NN + kvbase + krow)*DHH + ksl*8);
      *(short8*)((char*)&Ks[g2][0][0] + krow*256 + ((ksl ^ (krow&7))<<4)) = kv;
      const int vrow = s >> 3, vsl = s & 7;
      short8 vv = *(const short8*)(Vtg + ((size_t)bh*DHH + vrow)*NN + kvbase + vsl*8);
      *(short8*)((char*)&Vs[g2][0][0] + vrow*128 + ((vsl ^ (vrow&7))<<4)) = vv;
    }
  }
  __syncthreads();

  const int NT2 = 16;
  for (int t = 0; t < NT2; ++t){
    const int cur = t & 1;
    short8 kst[3], vst[3];
    if (t + 1 < NT2){
      const int kv0 = kvbase + (t+1)*64;
      #pragma unroll
      for (int it = 0; it < 3; ++it){
        const int s = gtid + it*256;
        const int krow = s/12, ksl = s%12;
        kst[it] = *(const short8*)(Kg + ((size_t)bh*NN + kv0 + krow)*DHH + ksl*8);
        const int vrow = s >> 3, vsl = s & 7;
        vst[it] = *(const short8*)(Vtg + ((size_t)bh*DHH + vrow)*NN + kv0 + vsl*8);
      }
    }
    f32x16 s0, s1;
    #pragma unroll
    for (int r = 0; r < 16; ++r){ s0[r]=0.f; s1[r]=0.f; }
    #pragma unroll
    for (int ks = 0; ks < 6; ++ks){
      const int sl = ks*2 + hi;
      short8 kf0 = *(const short8*)((const char*)&Ks[g2][cur][0] + li*256      + ((sl ^ (li&7))<<4));
      short8 kf1 = *(const short8*)((const char*)&Ks[g2][cur][0] + (32+li)*256 + ((sl ^ ((32+li)&7))<<4));
      s0 = __builtin_amdgcn_mfma_f32_32x32x16_bf16(kf0, qf[ks], s0, 0, 0, 0);
      s1 = __builtin_amdgcn_mfma_f32_32x32x16_bf16(kf1, qf[ks], s1, 0, 0, 0);
    }
    float ps = 0.f;
    #pragma unroll
    for (int r = 0; r < 16; ++r){
      float pa = __expf(s0[r] - SMAXC);
      float pb = __expf(s1[r] - SMAXC);
      s0[r] = pa; s1[r] = pb; ps += pa + pb;
    }
    ps += __shfl_xor(ps, 32);
    lrun += ps;
    short8 pa0, pa1, pa2, pa3;
    BUILD_PA(pa0, s0, 0); BUILD_PA(pa1, s0, 8);
    BUILD_PA(pa2, s1, 0); BUILD_PA(pa3, s1, 8);
    #pragma unroll
    for (int dt = 0; dt < 3; ++dt){
      const int drow = dt*32 + li;
      const char* vb_base = (const char*)&Vs[g2][cur][0] + drow*128;
      f32x16* op = (dt==0)? &o0 : (dt==1)? &o1 : &o2;
      {
        short8 vb = *(const short8*)(vb_base + (((0*2+hi) ^ (drow&7))<<4));
        *op = __builtin_amdgcn_mfma_f32_32x32x16_bf16(pa0, vb, *op, 0, 0, 0);
      }
      {
        short8 vb = *(const short8*)(vb_base + (((1*2+hi) ^ (drow&7))<<4));
        *op = __builtin_amdgcn_mfma_f32_32x32x16_bf16(pa1, vb, *op, 0, 0, 0);
      }
      {
        short8 vb = *(const short8*)(vb_base + (((2*2+hi) ^ (drow&7))<<4));
        *op = __builtin_amdgcn_mfma_f32_32x32x16_bf16(pa2, vb, *op, 0, 0, 0);
      }
      {
        short8 vb = *(const short8*)(vb_base + (((3*2+hi) ^ (drow&7))<<4));
        *op = __builtin_amdgcn_mfma_f32_32x32x16_bf16(pa3, vb, *op, 0, 0, 0);
      }
    }
    __syncthreads();
    if (t + 1 < NT2){
      #pragma unroll
      for (int it = 0; it < 3; ++it){
        const int s = gtid + it*256;
        const int krow = s/12, ksl = s%12;
        *(short8*)((char*)&Ks[g2][cur^1][0] + krow*256 + ((ksl ^ (krow&7))<<4)) = kst[it];
        const int vrow = s >> 3, vsl = s & 7;
        *(short8*)((char*)&Vs[g2][cur^1][0] + vrow*128 + ((vsl ^ (vrow&7))<<4)) = vst[it];
      }
      __syncthreads();
    }
  }

  float* cmb = (float*)&Ks[0][0][0];
  float* cl  = (float*)&Vs[0][0][0];
  if (g2 == 1){
    #pragma unroll
    for (int r = 0; r < 16; ++r){
      cmb[((wq*16 + r)*3 + 0)*64 + l] = o0[r];
      cmb[((wq*16 + r)*3 + 1)*64 + l] = o1[r];
      cmb[((wq*16 + r)*3 + 2)*64 + l] = o2[r];
    }
    if (l < 32) cl[wq*32 + l] = lrun;
  }
  __syncthreads();
  if (g2 == 0){
    #pragma unroll
    for (int r = 0; r < 16; ++r){
      o0[r] += cmb[((wq*16 + r)*3 + 0)*64 + l];
      o1[r] += cmb[((wq*16 + r)*3 + 1)*64 + l];
      o2[r] += cmb[((wq*16 + r)*3 + 2)*64 + l];
    }
    lrun += cl[wq*32 + li];
    const float linv = 1.f / lrun;
    #pragma unroll
    for (int r = 0; r < 16; ++r){
      const float lr = __shfl(linv, CROW(r), 64);
      const int n = q0w + CROW(r);
      u16* dst = AO + ((size_t)b*NN + n)*DIMM + h*DHH + li;
      dst[0]  = f2b(o0[r]*lr);
      dst[32] = f2b(o1[r]*lr);
      dst[64] = f2b(o2[r]*lr);
    }
  }
}

// ---------------- workspace layout (bytes) ----------------
static constexpr size_t W_QKV1T = 0;
static constexpr size_t W_QKV2T = W_QKV1T + 3538944;
static constexpr size_t W_OUTT  = W_QKV2T + 3538944;
static constexpr size_t W_M1W1T = W_OUTT  + 1179648;
static constexpr size_t W_M1W2T = W_M1W1T + 4718592;
static constexpr size_t W_M2W1T = W_M1W2T + 4718592;
static constexpr size_t W_M2W2T = W_M2W1T + 4718592;
static constexpr size_t O_MODH  = W_M2W2T + 4718592;
static constexpr size_t O_MODB  = O_MODH + 4096;
static constexpr size_t DYN     = O_MODB + 73728;
static constexpr size_t O_XM1   = DYN;
static constexpr size_t O_XM2   = O_XM1 + 3145728;
static constexpr size_t O_QKV1  = O_XM2 + 3145728;
static constexpr size_t O_QKV2  = O_QKV1 + 9437184;
static constexpr size_t O_QB    = O_QKV2 + 9437184;
static constexpr size_t O_KB    = O_QB + 6291456;
static constexpr size_t O_VTMP  = O_KB + 6291456;
static constexpr size_t O_PF    = O_VTMP + 6291456;
static constexpr size_t O_VT    = O_QKV1;
static constexpr size_t O_AO    = O_QKV2;
static constexpr size_t O_H1    = O_QB;
static constexpr size_t O_H2    = O_PF;

extern "C" void kernel_launch(void* const* d_in, const int* in_sizes, int n_in,
                              void* d_out, int out_size, void* d_ws, size_t ws_size,
                              hipStream_t stream){
  const float* x_s1   = (const float*)d_in[0];
  const float* x_s2   = (const float*)d_in[1];
  const float* p_emb  = (const float*)d_in[2];
  const float* mod_w1 = (const float*)d_in[3];
  const float* mod_b1 = (const float*)d_in[4];
  const float* mod_w2 = (const float*)d_in[5];
  const float* mod_b2 = (const float*)d_in[6];
  const float* n11_w  = (const float*)d_in[7];
  const float* n12_w  = (const float*)d_in[8];
  const float* qkv_w  = (const float*)d_in[9];
  const float* qkv_b  = (const float*)d_in[10];
  const float* qkv2_w = (const float*)d_in[11];
  const float* qkv2_b = (const float*)d_in[12];
  const float* qk_sc  = (const float*)d_in[13];
  const float* out_w  = (const float*)d_in[14];
  const float* out_b  = (const float*)d_in[15];
  const float* n21_w  = (const float*)d_in[16];
  const float* n22_w  = (const float*)d_in[17];
  const float* m1w1   = (const float*)d_in[18];
  const float* m1b1   = (const float*)d_in[19];
  const float* m1w2   = (const float*)d_in[20];
  const float* m1b2   = (const float*)d_in[21];
  const float* m2w1   = (const float*)d_in[22];
  const float* m2b1   = (const float*)d_in[23];
  const float* m2w2   = (const float*)d_in[24];
  const float* m2b2   = (const float*)d_in[25];

  char* ws = (char*)d_ws;
  u16* qkv1t = (u16*)(ws + W_QKV1T);
  u16* qkv2t = (u16*)(ws + W_QKV2T);
  u16* outt  = (u16*)(ws + W_OUTT);
  u16* w11t  = (u16*)(ws + W_M1W1T);
  u16* w12t  = (u16*)(ws + W_M1W2T);
  u16* w21t  = (u16*)(ws + W_M2W1T);
  u16* w22t  = (u16*)(ws + W_M2W2T);
  float* h2b  = (float*)(ws + O_MODH);
  float* modb = (float*)(ws + O_MODB);
  u16* xm1  = (u16*)(ws + O_XM1);
  u16* xm2  = (u16*)(ws + O_XM2);
  u16* qkv1 = (u16*)(ws + O_QKV1);
  u16* qkv2 = (u16*)(ws + O_QKV2);
  u16* Qb   = (u16*)(ws + O_QB);
  u16* Kb   = (u16*)(ws + O_KB);
  u16* Vtmp = (u16*)(ws + O_VTMP);
  u16* Vt   = (u16*)(ws + O_VT);
  u16* AO   = (u16*)(ws + O_AO);
  u16* H1   = (u16*)(ws + O_H1);
  u16* H2   = (u16*)(ws + O_H2);

  float* out0 = (float*)d_out;
  float* out1 = out0 + (size_t)BB*TT*DIMM;

  wt_all_k<<<13248, 256, 0, stream>>>(qkv_w, qkv1t, qkv2_w, qkv2t, out_w, outt,
                                      m1w1, w11t, m1w2, w12t, m2w1, w21t, m2w2, w22t);

  mod_stage1_k<<<4, 256, 0, stream>>>(p_emb, mod_w1, mod_b1, h2b);
  mod_stage2_k<<<72, 256, 0, stream>>>(h2b, mod_w2, mod_b2, modb);

  rmsnorm2_k<<<2*BB*TT, 256, 0, stream>>>(x_s1, n11_w, 0, 1, xm1,
                                          x_s2, n12_w, 3, 4, xm2, modb);

  // QKV GEMMs (dual, pipelined): [2048,768]@[768,2304] -> bf16
  gemm_pipe_k<1,1><<<dim3(18, 16, 2), 256, 0, stream>>>(
      xm1, qkv1t, qkv_b, qkv1, xm2, qkv2t, qkv2_b, qkv2, 2048, 2304, 768);

  build_qkv_k<<<(BB*NHEADS*NN)/4, 256, 0, stream>>>(qkv1, qkv2, qk_sc, Qb, Kb, Vtmp);

  vtrans_k<<<dim3(NN/32, DHH/32, 16), 256, 0, stream>>>(Vtmp, Vt);

  attn_mfma_k<<<16*16, 512, 0, stream>>>(Qb, Kb, Vt, AO);

  // out projection + fused gated residual -> d_out (16-wave split-K)
  gemm16_k<3,0><<<192, 1024, 0, stream>>>(
      AO, outt, out_b, AO, outt, out_b,
      modb, x_s1, x_s2, out0, out1, 2, 5, 4096, 768, 768);

  rmsnorm2_k<<<2*BB*TT, 256, 0, stream>>>(out0, n21_w, 6, 7, xm1,
                                          out1, n22_w, 9, 10, xm2, modb);

  // MLP up (dual, GELU, pipelined) -> bf16
  gemm_pipe_k<2,1><<<dim3(24, 16, 2), 256, 0, stream>>>(
      xm1, w11t, m1b1, H1, xm2, w21t, m2b1, H2, 2048, 3072, 768);

  // MLP down (dual) + fused final gated add (16-wave split-K)
  gemm16_k<4,1><<<192, 1024, 0, stream>>>(
      H1, w12t, m1b2, H2, w22t, m2b2,
      modb, nullptr, nullptr, out0, out1, 8, 11, 2048, 768, 3072);
}

// Round 6
// 281.015 us; speedup vs baseline: 1.0040x; 1.0040x over previous
//
#include <hip/hip_runtime.h>
#include <hip/hip_bf16.h>
#include <cstdint>
#include <math.h>

#define BB 2
#define TT 1024
#define DIMM 768
#define NHEADS 8
#define DHH 96
#define MLPD 3072
#define NN 2048   // 2*T

typedef unsigned short u16;
using short8 = __attribute__((ext_vector_type(8))) short;
using f32x4  = __attribute__((ext_vector_type(4))) float;
using f32x16 = __attribute__((ext_vector_type(16))) float;
using int4v  = __attribute__((ext_vector_type(4))) int;
union S8I4 { int4v i; short8 s; };

static constexpr float kEps = 1e-6f;

__device__ __forceinline__ float siluf(float x){ return x / (1.f + expf(-x)); }
__device__ __forceinline__ float geluf(float x){ return 0.5f*x*(1.f + erff(x*0.7071067811865475f)); }
__device__ __forceinline__ float bf16_rne(float x){
  uint32_t u = __float_as_uint(x);
  u = (u + 0x7fffu + ((u >> 16) & 1u)) & 0xffff0000u;
  return __uint_as_float(u);
}
__device__ __forceinline__ u16 f2b(float x){
  uint32_t u = __float_as_uint(x);
  return (u16)((u + 0x7fffu + ((u >> 16) & 1u)) >> 16);
}
__device__ __forceinline__ float b2f(u16 b){
  return __uint_as_float(((uint32_t)b) << 16);
}
__device__ __forceinline__ int cvtpk(float lo, float hi){
  int d; asm("v_cvt_pk_bf16_f32 %0, %1, %2" : "=v"(d) : "v"(lo), "v"(hi)); return d;
}
__device__ __forceinline__ void gload16(const void* g, void* l){
  __builtin_amdgcn_global_load_lds((const __attribute__((address_space(1))) unsigned int*)g,
                                   (__attribute__((address_space(3))) unsigned int*)l, 16, 0, 0);
}

// ---------------- modulation MLP (fp32, tiny) ----------------
__global__ __launch_bounds__(256) void mod_stage1_k(
    const float* __restrict__ p_emb, const float* __restrict__ w1,
    const float* __restrict__ b1, float* __restrict__ h2){
  __shared__ float sp[1024];
  const int b = blockIdx.x >> 1;
  const int obase = (blockIdx.x & 1) * 256;
  for (int i = threadIdx.x; i < 1024; i += 256)
    sp[i] = siluf(p_emb[b*1024 + i]);
  __syncthreads();
  const int o = obase + threadIdx.x;
  float acc = 0.f;
  for (int j = 0; j < 1024; ++j) acc += sp[j] * w1[j*512 + o];
  h2[b*512 + o] = siluf(acc + b1[o]);
}

__global__ __launch_bounds__(256) void mod_stage2_k(
    const float* __restrict__ h2, const float* __restrict__ w2,
    const float* __restrict__ b2, float* __restrict__ mod){
  __shared__ float sh[512];
  const int b = blockIdx.x / 36;
  const int obase = (blockIdx.x % 36) * 256;
  for (int i = threadIdx.x; i < 512; i += 256)
    sh[i] = h2[b*512 + i];
  __syncthreads();
  const int o = obase + threadIdx.x;
  float acc = 0.f;
  for (int j = 0; j < 512; ++j) acc += sh[j] * w2[j*9216 + o];
  mod[b*9216 + o] = acc + b2[o];
}

// ------------- fused weight convert+transpose (all 7 weights, 1 launch) -----
__global__ __launch_bounds__(256) void wt_all_k(
    const float* __restrict__ s0, u16* __restrict__ d0,
    const float* __restrict__ s1, u16* __restrict__ d1,
    const float* __restrict__ s2, u16* __restrict__ d2,
    const float* __restrict__ s3, u16* __restrict__ d3,
    const float* __restrict__ s4, u16* __restrict__ d4,
    const float* __restrict__ s5, u16* __restrict__ d5,
    const float* __restrict__ s6, u16* __restrict__ d6){
  const int bid = blockIdx.x;
  const float* S; u16* D; int K, N, lid;
  if      (bid < 1728) { S=s0; D=d0; K=768;  N=2304; lid=bid; }
  else if (bid < 3456) { S=s1; D=d1; K=768;  N=2304; lid=bid-1728; }
  else if (bid < 4032) { S=s2; D=d2; K=768;  N=768;  lid=bid-3456; }
  else if (bid < 6336) { S=s3; D=d3; K=768;  N=3072; lid=bid-4032; }
  else if (bid < 8640) { S=s4; D=d4; K=3072; N=768;  lid=bid-6336; }
  else if (bid < 10944){ S=s5; D=d5; K=768;  N=3072; lid=bid-8640; }
  else                 { S=s6; D=d6; K=3072; N=768;  lid=bid-10944; }
  const int nx = N >> 5;
  const int k0 = (lid / nx) * 32, n0 = (lid % nx) * 32;
  __shared__ float t[32][33];
  const int tx = threadIdx.x & 31, ty = threadIdx.x >> 5;
  for (int i = ty; i < 32; i += 8)
    t[i][tx] = S[(size_t)(k0+i)*N + n0 + tx];
  __syncthreads();
  for (int i = ty; i < 32; i += 8)
    D[(size_t)(n0+i)*K + k0 + tx] = f2b(t[tx][i]);
}

// ---------------- RMSNorm + modulation -> bf16 (both streams, 1 launch) ----
__global__ __launch_bounds__(256) void rmsnorm2_k(
    const float* __restrict__ x0, const float* __restrict__ w0, int cs0, int ch0, u16* __restrict__ o0,
    const float* __restrict__ x1, const float* __restrict__ w1, int cs1, int ch1, u16* __restrict__ o1,
    const float* __restrict__ mod){
  const int rowg = blockIdx.x;
  const int s = rowg >> 11;
  const int row = rowg & 2047;
  const float* x = s ? x1 : x0;
  const float* w = s ? w1 : w0;
  const int cs = s ? cs1 : cs0, ch = s ? ch1 : ch0;
  u16* out = s ? o1 : o0;
  const int b = row >> 10;
  const int tid = threadIdx.x;
  const float* xr = x + (size_t)row * DIMM;
  float v0 = xr[tid], v1 = xr[tid + 256], v2 = xr[tid + 512];
  float ss = v0*v0 + v1*v1 + v2*v2;
  __shared__ float red[4];
  for (int m = 1; m < 64; m <<= 1) ss += __shfl_xor(ss, m, 64);
  if ((tid & 63) == 0) red[tid >> 6] = ss;
  __syncthreads();
  float tot = red[0] + red[1] + red[2] + red[3];
  float rms = rsqrtf(tot * (1.f/768.f) + kEps);
  const float* ms = mod + (size_t)b*9216 + (size_t)cs*768;
  const float* mh = mod + (size_t)b*9216 + (size_t)ch*768;
  u16* orow = out + (size_t)row * DIMM;
  orow[tid]       = f2b(v0*rms*w[tid]      *(1.f+ms[tid])       + mh[tid]);
  orow[tid + 256] = f2b(v1*rms*w[tid+256]  *(1.f+ms[tid+256])   + mh[tid+256]);
  orow[tid + 512] = f2b(v2*rms*w[tid+512]  *(1.f+ms[tid+512])   + mh[tid+512]);
}

// ------- pipelined 4-wave bf16 MFMA GEMM (QKV, MLP-up): 128x128, BK=32 -----
// Triple-buffered LDS, loads 2 tiles ahead, counted vmcnt, raw s_barrier.
// T2 slot-XOR swizzle: LDS rows are 64B (4x16B slots); slot ^= (row>>1)&3.
// global_load_lds writes linearly -> inverse swizzle applied to GLOBAL col.
// EPI: 1 = bf16 store; 2 = gelu->bf16 store.
template<int EPI, int DUAL>
__global__ __launch_bounds__(256) void gemm_pipe_k(
    const u16* __restrict__ A0, const u16* __restrict__ Bt0,
    const float* __restrict__ bias0, void* __restrict__ C0,
    const u16* __restrict__ A1, const u16* __restrict__ Bt1,
    const float* __restrict__ bias1, void* __restrict__ C1,
    int M, int N, int K){
  __shared__ u16 As[3][128*32];
  __shared__ u16 Bs[3][128*32];
  const int z = DUAL ? blockIdx.z : 0;
  const u16* A      = z ? A1 : A0;
  const u16* Bt     = z ? Bt1 : Bt0;
  const float* bias = z ? bias1 : bias0;
  void* C           = z ? C1 : C0;
  const int tid = threadIdx.x;
  const int w = tid >> 6, l = tid & 63;
  const int m0 = blockIdx.y*128, n0 = blockIdx.x*128;
  const int wr = w >> 1, wc = w & 1;
  const int la = l & 15, hi4 = l >> 4;
  f32x4 acc[4][4] = {};
  const int nk = K >> 5;
  // per-thread staging coords; source col pre-swizzled (inverse of read swz)
  const int sb0 = w*128, sb1 = w*128 + 64;
  const int s0i = sb0 + l, s1i = sb1 + l;
  const int r0 = s0i >> 2, c0 = ((s0i & 3) ^ ((r0 >> 1) & 3)) * 8;
  const int r1 = s1i >> 2, c1 = ((s1i & 3) ^ ((r1 >> 1) & 3)) * 8;
  const u16* Ar0 = A  + (size_t)(m0+r0)*K + c0;
  const u16* Ar1 = A  + (size_t)(m0+r1)*K + c1;
  const u16* Br0 = Bt + (size_t)(n0+r0)*K + c0;
  const u16* Br1 = Bt + (size_t)(n0+r1)*K + c1;
  #define STAGE(buf, kofs) { \
    gload16(Ar0 + (kofs), &As[buf][sb0*8]); \
    gload16(Br0 + (kofs), &Bs[buf][sb0*8]); \
    gload16(Ar1 + (kofs), &As[buf][sb1*8]); \
    gload16(Br1 + (kofs), &Bs[buf][sb1*8]); }
  STAGE(0, 0);
  STAGE(1, 32);
  // read-side swizzled slot byte offset: (hi4 ^ ((la>>1)&3))*16, lane-constant
  const int rslot = ((hi4 ^ ((l >> 1) & 3)) << 4);
  int cur = 0;
  for (int kt = 0; kt < nk; ++kt){
    if (kt + 1 < nk){ asm volatile("s_waitcnt vmcnt(4)" ::: "memory"); }
    else            { asm volatile("s_waitcnt vmcnt(0)" ::: "memory"); }
    __builtin_amdgcn_s_barrier();
    if (kt + 2 < nk){
      int nb = cur + 2; if (nb >= 3) nb -= 3;
      STAGE(nb, (kt+2) << 5);
    }
    short8 af[4], bf[4];
    #pragma unroll
    for (int mi = 0; mi < 4; ++mi)
      af[mi] = *(const short8*)((const char*)&As[cur][0] + (wr*64 + mi*16 + la)*64 + rslot);
    #pragma unroll
    for (int ni = 0; ni < 4; ++ni)
      bf[ni] = *(const short8*)((const char*)&Bs[cur][0] + (wc*64 + ni*16 + la)*64 + rslot);
    #pragma unroll
    for (int mi = 0; mi < 4; ++mi)
      #pragma unroll
      for (int ni = 0; ni < 4; ++ni)
        acc[mi][ni] = __builtin_amdgcn_mfma_f32_16x16x32_bf16(af[mi], bf[ni], acc[mi][ni], 0, 0, 0);
    if (++cur == 3) cur = 0;
  }
  #undef STAGE
  #pragma unroll
  for (int mi = 0; mi < 4; ++mi){
    #pragma unroll
    for (int ni = 0; ni < 4; ++ni){
      const int n = n0 + wc*64 + ni*16 + la;
      const float bv = bias[n];
      #pragma unroll
      for (int rr = 0; rr < 4; ++rr){
        const int m = m0 + wr*64 + mi*16 + hi4*4 + rr;
        float v = acc[mi][ni][rr] + bv;
        if constexpr (EPI == 2) v = geluf(v);
        ((u16*)C)[(size_t)m*N + n] = f2b(v);
      }
    }
  }
}

// ---------------- 16-wave split-K=4 GEMM (192-block shapes, N=768) ---------
// 1024 threads = 4 K-groups x 4 waves; 128x128 tile; combine via LDS.
// Same T2 slot-XOR swizzle as gemm_pipe_k.
// EPI: 3 = O = X + (v)*gate (outproj+residual); 4 = O += v*gate (final add).
template<int EPI, int DUAL>
__global__ __launch_bounds__(1024) void gemm16_k(
    const u16* __restrict__ A0, const u16* __restrict__ Bt0,
    const float* __restrict__ bias0,
    const u16* __restrict__ A1, const u16* __restrict__ Bt1,
    const float* __restrict__ bias1,
    const float* __restrict__ mod, const float* __restrict__ X0,
    const float* __restrict__ X1, float* __restrict__ O0,
    float* __restrict__ O1, int cg0, int cg1,
    int M, int N, int K){
  __shared__ char lds[131072];   // 4 groups x 32KB staging; reused for combine
  const int bid = blockIdx.x;
  const int xcd = bid & 7, kk = bid >> 3;
  const int g = xcd + 8*(kk/6);      // 32 (y,z) panel groups, 6 x-blocks each
  const int x = kk % 6;
  int by, z;
  if constexpr (DUAL){ by = g & 15; z = g >> 4; } else { by = g; z = 0; }
  const u16* A      = z ? A1 : A0;
  const u16* Bt     = z ? Bt1 : Bt0;
  const float* bias = z ? bias1 : bias0;
  const int tid = threadIdx.x;
  const int w = tid >> 6, l = tid & 63;
  const int kg = w >> 2, gw = w & 3;
  const int m0 = by*128, n0 = x*128;
  const int wr = gw >> 1, wc = gw & 1;
  const int la = l & 15, hi4 = l >> 4;
  u16* AsG = (u16*)(lds + kg*32768);
  u16* BsG = (u16*)(lds + kg*32768 + 16384);
  const int Kg = K >> 2;
  const int nk = Kg >> 5;
  const int kbase = kg * Kg;
  f32x4 acc[4][4] = {};
  #pragma unroll
  for (int it = 0; it < 2; ++it){
    const int sb = gw*128 + it*64;
    const int s = sb + l;
    const int row = s >> 2, scol = ((s & 3) ^ ((row >> 1) & 3)) * 8;
    gload16(A  + (size_t)(m0+row)*K + kbase + scol, AsG + sb*8);
    gload16(Bt + (size_t)(n0+row)*K + kbase + scol, BsG + sb*8);
  }
  __syncthreads();
  const int rslot = (hi4 ^ ((l >> 1) & 3)) * 8;   // u16 units
  for (int kt = 0; kt < nk; ++kt){
    const int cur = kt & 1;
    if (kt + 1 < nk){
      const int k0n = kbase + ((kt+1) << 5);
      #pragma unroll
      for (int it = 0; it < 2; ++it){
        const int sb = gw*128 + it*64;
        const int s = sb + l;
        const int row = s >> 2, scol = ((s & 3) ^ ((row >> 1) & 3)) * 8;
        gload16(A  + (size_t)(m0+row)*K + k0n + scol, AsG + (cur^1)*4096 + sb*8);
        gload16(Bt + (size_t)(n0+row)*K + k0n + scol, BsG + (cur^1)*4096 + sb*8);
      }
    }
    short8 af[4], bf[4];
    #pragma unroll
    for (int mi = 0; mi < 4; ++mi)
      af[mi] = *(const short8*)(AsG + cur*4096 + (wr*64 + mi*16 + la)*32 + rslot);
    #pragma unroll
    for (int ni = 0; ni < 4; ++ni)
      bf[ni] = *(const short8*)(BsG + cur*4096 + (wc*64 + ni*16 + la)*32 + rslot);
    #pragma unroll
    for (int mi = 0; mi < 4; ++mi)
      #pragma unroll
      for (int ni = 0; ni < 4; ++ni)
        acc[mi][ni] = __builtin_amdgcn_mfma_f32_16x16x32_bf16(af[mi], bf[ni], acc[mi][ni], 0, 0, 0);
    __syncthreads();
  }
  // combine the 4 K-group partials through LDS (tree: {1->0, 3->2} then {2->0})
  float* c0 = (float*)lds;
  float* c1 = (float*)(lds + 65536);
  #define WRACC(cb) { \
    _Pragma("unroll") for (int mi = 0; mi < 4; ++mi) \
    _Pragma("unroll") for (int ni = 0; ni < 4; ++ni) \
    _Pragma("unroll") for (int rr = 0; rr < 4; ++rr) \
      (cb)[(wr*64+mi*16+hi4*4+rr)*128 + wc*64+ni*16+la] = acc[mi][ni][rr]; }
  #define RDACC(cb) { \
    _Pragma("unroll") for (int mi = 0; mi < 4; ++mi) \
    _Pragma("unroll") for (int ni = 0; ni < 4; ++ni) \
    _Pragma("unroll") for (int rr = 0; rr < 4; ++rr) \
      acc[mi][ni][rr] += (cb)[(wr*64+mi*16+hi4*4+rr)*128 + wc*64+ni*16+la]; }
  if (kg == 1) WRACC(c0);
  if (kg == 3) WRACC(c1);
  __syncthreads();
  if (kg == 0) RDACC(c0);
  if (kg == 2) RDACC(c1);
  __syncthreads();
  if (kg == 2) WRACC(c0);
  __syncthreads();
  if (kg == 0){
    RDACC(c0);
    #pragma unroll
    for (int mi = 0; mi < 4; ++mi){
      #pragma unroll
      for (int ni = 0; ni < 4; ++ni){
        const int n = n0 + wc*64 + ni*16 + la;
        const float bv = bias[n];
        #pragma unroll
        for (int rr = 0; rr < 4; ++rr){
          const int m = m0 + wr*64 + mi*16 + hi4*4 + rr;
          float v = acc[mi][ni][rr] + bv;
          if constexpr (EPI == 3){
            const int bb = m >> 11, ss = (m >> 10) & 1, t = m & 1023;
            const float* X = ss ? X1 : X0;
            float* O = ss ? O1 : O0;
            const float gmod = mod[(size_t)bb*9216 + (size_t)(ss ? cg1 : cg0)*768 + n];
            const size_t oi = ((size_t)(bb*1024 + t))*768 + n;
            O[oi] = X[oi] + v*gmod;
          } else {
            float* O = z ? O1 : O0;
            const int cg = z ? cg1 : cg0;
            const int bb = m >> 10;
            const float gmod = mod[(size_t)bb*9216 + (size_t)cg*768 + n];
            O[(size_t)m*N + n] += v*gmod;
          }
        }
      }
    }
  }
  #undef WRACC
  #undef RDACC
}

// ---------------- head split + RoPE + L2norm*scale (bf16 io) ---------------
__global__ __launch_bounds__(256) void build_qkv_k(
    const u16* __restrict__ qkv1, const u16* __restrict__ qkv2,
    const float* __restrict__ qk_scale,
    u16* __restrict__ Q, u16* __restrict__ K, u16* __restrict__ V){
  const int wid = threadIdx.x >> 6;
  const int lane = threadIdx.x & 63;
  const int row = blockIdx.x * 4 + wid;         // (b*8+h)*2048 + n
  const int n = row & 2047;
  const int h = (row >> 11) & 7;
  const int b = row >> 14;
  const u16* src = (n < TT) ? (qkv1 + ((size_t)b*TT + n) * 2304)
                            : (qkv2 + ((size_t)b*TT + (n - TT)) * 2304);
  const int col = h * DHH;
  const bool act = lane < 48;
  float q0=0,q1=0,k0=0,k1=0,v0=0,v1=0,c=1.f,s=0.f,sc0=0,sc1=0;
  if (act){
    q0 = b2f(src[col + lane]);        q1 = b2f(src[col + lane + 48]);
    k0 = b2f(src[768 + col + lane]);  k1 = b2f(src[768 + col + lane + 48]);
    v0 = b2f(src[1536 + col + lane]); v1 = b2f(src[1536 + col + lane + 48]);
    float inv = bf16_rne((float)(1.0 / pow(10000.0, (2.0 * lane) / 96.0)));
    float ang = (float)n * inv;
    c = cosf(ang); s = sinf(ang);
    sc0 = qk_scale[lane]; sc1 = qk_scale[lane + 48];
  }
  float qr0 = q0*c - q1*s, qr1 = q1*c + q0*s;
  float kr0 = k0*c - k1*s, kr1 = k1*c + k0*s;
  float ssq = qr0*qr0 + qr1*qr1;
  float ssk = kr0*kr0 + kr1*kr1;
  for (int m = 1; m < 64; m <<= 1){ ssq += __shfl_xor(ssq, m, 64); ssk += __shfl_xor(ssk, m, 64); }
  float rq = 1.f / fmaxf(sqrtf(ssq), 1e-12f);
  float rk = 1.f / fmaxf(sqrtf(ssk), 1e-12f);
  const float sscale = 0.1020620726159658f;  // 96^-0.5 folded into Q
  if (act){
    size_t base = (size_t)row * DHH;
    Q[base + lane]      = f2b(qr0*rq*sc0*sscale);  Q[base + lane + 48] = f2b(qr1*rq*sc1*sscale);
    K[base + lane]      = f2b(kr0*rk*sc0);         K[base + lane + 48] = f2b(kr1*rk*sc1);
    V[base + lane]      = f2b(v0);                 V[base + lane + 48] = f2b(v1);
  }
}

// ---------------- V transpose: Vtmp[bh][n][96] -> Vt[bh][96][2048] ----------
__global__ __launch_bounds__(256) void vtrans_k(
    const u16* __restrict__ Vtmp, u16* __restrict__ Vt){
  __shared__ u16 t[32][33];
  const int bh = blockIdx.z;
  const int n0 = blockIdx.x*32, d0 = blockIdx.y*32;
  const int tx = threadIdx.x & 31, ty = threadIdx.x >> 5;
  for (int i = ty; i < 32; i += 8)
    t[i][tx] = Vtmp[((size_t)bh*NN + n0+i)*DHH + d0 + tx];
  __syncthreads();
  for (int i = ty; i < 32; i += 8)
    Vt[((size_t)bh*DHH + d0+i)*NN + n0 + tx] = t[tx][i];
}

// ---------------- MFMA flash attention, 8 waves = 2 KV-split groups --------
#define CROW(r) (((r)&3) + 8*((r)>>2) + 4*hi)
#define SMAXC 10.5f
#define BUILD_PA(dst, vec, basei) { \
  int a1_ = cvtpk(vec[basei+0], vec[basei+1]); \
  int b1_ = cvtpk(vec[basei+4], vec[basei+5]); \
  asm("v_permlane32_swap_b32 %0, %1" : "+v"(a1_), "+v"(b1_)); \
  int a2_ = cvtpk(vec[basei+2], vec[basei+3]); \
  int b2_ = cvtpk(vec[basei+6], vec[basei+7]); \
  asm("v_permlane32_swap_b32 %0, %1" : "+v"(a2_), "+v"(b2_)); \
  S8I4 u_; u_.i = (int4v){a1_, a2_, b1_, b2_}; dst = u_.s; }

__global__ __launch_bounds__(512) void attn_mfma_k(
    const u16* __restrict__ Qg, const u16* __restrict__ Kg,
    const u16* __restrict__ Vtg, u16* __restrict__ AO){
  __shared__ u16 Ks[2][2][64*128];   // [group][buf]; 64 rows x 256B, XOR-swizzled
  __shared__ u16 Vs[2][2][96*64];    // [group][buf]; 96 rows x 128B, XOR-swizzled
  const int bh = blockIdx.x >> 4;
  const int qblk = blockIdx.x & 15;
  const int b = bh >> 3, h = bh & 7;
  const int tid = threadIdx.x;
  const int w = tid >> 6, l = tid & 63;
  const int g2 = w >> 2, wq = w & 3;
  const int gtid = tid & 255;
  const int hi = l >> 5, li = l & 31;
  const int q0w = qblk*128 + wq*32;
  const int kvbase = g2 * 1024;

  short8 qf[6];
  {
    const u16* qrow = Qg + ((size_t)bh*NN + q0w + li)*DHH;
    #pragma unroll
    for (int ks = 0; ks < 6; ++ks)
      qf[ks] = *(const short8*)(qrow + ks*16 + hi*8);
  }

  f32x16 o0, o1, o2;
  #pragma unroll
  for (int r = 0; r < 16; ++r){ o0[r]=0.f; o1[r]=0.f; o2[r]=0.f; }
  float lrun = 0.f;

  {
    #pragma unroll
    for (int it = 0; it < 3; ++it){
      const int s = gtid + it*256;
      const int krow = s/12, ksl = s%12;
      short8 kv = *(const short8*)(Kg + ((size_t)bh*NN + kvbase + krow)*DHH + ksl*8);
      *(short8*)((char*)&Ks[g2][0][0] + krow*256 + ((ksl ^ (krow&7))<<4)) = kv;
      const int vrow = s >> 3, vsl = s & 7;
      short8 vv = *(const short8*)(Vtg + ((size_t)bh*DHH + vrow)*NN + kvbase + vsl*8);
      *(short8*)((char*)&Vs[g2][0][0] + vrow*128 + ((vsl ^ (vrow&7))<<4)) = vv;
    }
  }
  __syncthreads();

  const int NT2 = 16;
  for (int t = 0; t < NT2; ++t){
    const int cur = t & 1;
    short8 kst[3], vst[3];
    if (t + 1 < NT2){
      const int kv0 = kvbase + (t+1)*64;
      #pragma unroll
      for (int it = 0; it < 3; ++it){
        const int s = gtid + it*256;
        const int krow = s/12, ksl = s%12;
        kst[it] = *(const short8*)(Kg + ((size_t)bh*NN + kv0 + krow)*DHH + ksl*8);
        const int vrow = s >> 3, vsl = s & 7;
        vst[it] = *(const short8*)(Vtg + ((size_t)bh*DHH + vrow)*NN + kv0 + vsl*8);
      }
    }
    f32x16 s0, s1;
    #pragma unroll
    for (int r = 0; r < 16; ++r){ s0[r]=0.f; s1[r]=0.f; }
    #pragma unroll
    for (int ks = 0; ks < 6; ++ks){
      const int sl = ks*2 + hi;
      short8 kf0 = *(const short8*)((const char*)&Ks[g2][cur][0] + li*256      + ((sl ^ (li&7))<<4));
      short8 kf1 = *(const short8*)((const char*)&Ks[g2][cur][0] + (32+li)*256 + ((sl ^ ((32+li)&7))<<4));
      s0 = __builtin_amdgcn_mfma_f32_32x32x16_bf16(kf0, qf[ks], s0, 0, 0, 0);
      s1 = __builtin_amdgcn_mfma_f32_32x32x16_bf16(kf1, qf[ks], s1, 0, 0, 0);
    }
    float ps = 0.f;
    #pragma unroll
    for (int r = 0; r < 16; ++r){
      float pa = __expf(s0[r] - SMAXC);
      float pb = __expf(s1[r] - SMAXC);
      s0[r] = pa; s1[r] = pb; ps += pa + pb;
    }
    ps += __shfl_xor(ps, 32);
    lrun += ps;
    short8 pa0, pa1, pa2, pa3;
    BUILD_PA(pa0, s0, 0); BUILD_PA(pa1, s0, 8);
    BUILD_PA(pa2, s1, 0); BUILD_PA(pa3, s1, 8);
    #pragma unroll
    for (int dt = 0; dt < 3; ++dt){
      const int drow = dt*32 + li;
      const char* vb_base = (const char*)&Vs[g2][cur][0] + drow*128;
      f32x16* op = (dt==0)? &o0 : (dt==1)? &o1 : &o2;
      {
        short8 vb = *(const short8*)(vb_base + (((0*2+hi) ^ (drow&7))<<4));
        *op = __builtin_amdgcn_mfma_f32_32x32x16_bf16(pa0, vb, *op, 0, 0, 0);
      }
      {
        short8 vb = *(const short8*)(vb_base + (((1*2+hi) ^ (drow&7))<<4));
        *op = __builtin_amdgcn_mfma_f32_32x32x16_bf16(pa1, vb, *op, 0, 0, 0);
      }
      {
        short8 vb = *(const short8*)(vb_base + (((2*2+hi) ^ (drow&7))<<4));
        *op = __builtin_amdgcn_mfma_f32_32x32x16_bf16(pa2, vb, *op, 0, 0, 0);
      }
      {
        short8 vb = *(const short8*)(vb_base + (((3*2+hi) ^ (drow&7))<<4));
        *op = __builtin_amdgcn_mfma_f32_32x32x16_bf16(pa3, vb, *op, 0, 0, 0);
      }
    }
    __syncthreads();
    if (t + 1 < NT2){
      #pragma unroll
      for (int it = 0; it < 3; ++it){
        const int s = gtid + it*256;
        const int krow = s/12, ksl = s%12;
        *(short8*)((char*)&Ks[g2][cur^1][0] + krow*256 + ((ksl ^ (krow&7))<<4)) = kst[it];
        const int vrow = s >> 3, vsl = s & 7;
        *(short8*)((char*)&Vs[g2][cur^1][0] + vrow*128 + ((vsl ^ (vrow&7))<<4)) = vst[it];
      }
      __syncthreads();
    }
  }

  float* cmb = (float*)&Ks[0][0][0];
  float* cl  = (float*)&Vs[0][0][0];
  if (g2 == 1){
    #pragma unroll
    for (int r = 0; r < 16; ++r){
      cmb[((wq*16 + r)*3 + 0)*64 + l] = o0[r];
      cmb[((wq*16 + r)*3 + 1)*64 + l] = o1[r];
      cmb[((wq*16 + r)*3 + 2)*64 + l] = o2[r];
    }
    if (l < 32) cl[wq*32 + l] = lrun;
  }
  __syncthreads();
  if (g2 == 0){
    #pragma unroll
    for (int r = 0; r < 16; ++r){
      o0[r] += cmb[((wq*16 + r)*3 + 0)*64 + l];
      o1[r] += cmb[((wq*16 + r)*3 + 1)*64 + l];
      o2[r] += cmb[((wq*16 + r)*3 + 2)*64 + l];
    }
    lrun += cl[wq*32 + li];
    const float linv = 1.f / lrun;
    #pragma unroll
    for (int r = 0; r < 16; ++r){
      const float lr = __shfl(linv, CROW(r), 64);
      const int n = q0w + CROW(r);
      u16* dst = AO + ((size_t)b*NN + n)*DIMM + h*DHH + li;
      dst[0]  = f2b(o0[r]*lr);
      dst[32] = f2b(o1[r]*lr);
      dst[64] = f2b(o2[r]*lr);
    }
  }
}

// ---------------- workspace layout (bytes) ----------------
static constexpr size_t W_QKV1T = 0;
static constexpr size_t W_QKV2T = W_QKV1T + 3538944;
static constexpr size_t W_OUTT  = W_QKV2T + 3538944;
static constexpr size_t W_M1W1T = W_OUTT  + 1179648;
static constexpr size_t W_M1W2T = W_M1W1T + 4718592;
static constexpr size_t W_M2W1T = W_M1W2T + 4718592;
static constexpr size_t W_M2W2T = W_M2W1T + 4718592;
static constexpr size_t O_MODH  = W_M2W2T + 4718592;
static constexpr size_t O_MODB  = O_MODH + 4096;
static constexpr size_t DYN     = O_MODB + 73728;
static constexpr size_t O_XM1   = DYN;
static constexpr size_t O_XM2   = O_XM1 + 3145728;
static constexpr size_t O_QKV1  = O_XM2 + 3145728;
static constexpr size_t O_QKV2  = O_QKV1 + 9437184;
static constexpr size_t O_QB    = O_QKV2 + 9437184;
static constexpr size_t O_KB    = O_QB + 6291456;
static constexpr size_t O_VTMP  = O_KB + 6291456;
static constexpr size_t O_PF    = O_VTMP + 6291456;
static constexpr size_t O_VT    = O_QKV1;
static constexpr size_t O_AO    = O_QKV2;
static constexpr size_t O_H1    = O_QB;
static constexpr size_t O_H2    = O_PF;

extern "C" void kernel_launch(void* const* d_in, const int* in_sizes, int n_in,
                              void* d_out, int out_size, void* d_ws, size_t ws_size,
                              hipStream_t stream){
  const float* x_s1   = (const float*)d_in[0];
  const float* x_s2   = (const float*)d_in[1];
  const float* p_emb  = (const float*)d_in[2];
  const float* mod_w1 = (const float*)d_in[3];
  const float* mod_b1 = (const float*)d_in[4];
  const float* mod_w2 = (const float*)d_in[5];
  const float* mod_b2 = (const float*)d_in[6];
  const float* n11_w  = (const float*)d_in[7];
  const float* n12_w  = (const float*)d_in[8];
  const float* qkv_w  = (const float*)d_in[9];
  const float* qkv_b  = (const float*)d_in[10];
  const float* qkv2_w = (const float*)d_in[11];
  const float* qkv2_b = (const float*)d_in[12];
  const float* qk_sc  = (const float*)d_in[13];
  const float* out_w  = (const float*)d_in[14];
  const float* out_b  = (const float*)d_in[15];
  const float* n21_w  = (const float*)d_in[16];
  const float* n22_w  = (const float*)d_in[17];
  const float* m1w1   = (const float*)d_in[18];
  const float* m1b1   = (const float*)d_in[19];
  const float* m1w2   = (const float*)d_in[20];
  const float* m1b2   = (const float*)d_in[21];
  const float* m2w1   = (const float*)d_in[22];
  const float* m2b1   = (const float*)d_in[23];
  const float* m2w2   = (const float*)d_in[24];
  const float* m2b2   = (const float*)d_in[25];

  char* ws = (char*)d_ws;
  u16* qkv1t = (u16*)(ws + W_QKV1T);
  u16* qkv2t = (u16*)(ws + W_QKV2T);
  u16* outt  = (u16*)(ws + W_OUTT);
  u16* w11t  = (u16*)(ws + W_M1W1T);
  u16* w12t  = (u16*)(ws + W_M1W2T);
  u16* w21t  = (u16*)(ws + W_M2W1T);
  u16* w22t  = (u16*)(ws + W_M2W2T);
  float* h2b  = (float*)(ws + O_MODH);
  float* modb = (float*)(ws + O_MODB);
  u16* xm1  = (u16*)(ws + O_XM1);
  u16* xm2  = (u16*)(ws + O_XM2);
  u16* qkv1 = (u16*)(ws + O_QKV1);
  u16* qkv2 = (u16*)(ws + O_QKV2);
  u16* Qb   = (u16*)(ws + O_QB);
  u16* Kb   = (u16*)(ws + O_KB);
  u16* Vtmp = (u16*)(ws + O_VTMP);
  u16* Vt   = (u16*)(ws + O_VT);
  u16* AO   = (u16*)(ws + O_AO);
  u16* H1   = (u16*)(ws + O_H1);
  u16* H2   = (u16*)(ws + O_H2);

  float* out0 = (float*)d_out;
  float* out1 = out0 + (size_t)BB*TT*DIMM;

  wt_all_k<<<13248, 256, 0, stream>>>(qkv_w, qkv1t, qkv2_w, qkv2t, out_w, outt,
                                      m1w1, w11t, m1w2, w12t, m2w1, w21t, m2w2, w22t);

  mod_stage1_k<<<4, 256, 0, stream>>>(p_emb, mod_w1, mod_b1, h2b);
  mod_stage2_k<<<72, 256, 0, stream>>>(h2b, mod_w2, mod_b2, modb);

  rmsnorm2_k<<<2*BB*TT, 256, 0, stream>>>(x_s1, n11_w, 0, 1, xm1,
                                          x_s2, n12_w, 3, 4, xm2, modb);

  // QKV GEMMs (dual, pipelined, swizzled): [2048,768]@[768,2304] -> bf16
  gemm_pipe_k<1,1><<<dim3(18, 16, 2), 256, 0, stream>>>(
      xm1, qkv1t, qkv_b, qkv1, xm2, qkv2t, qkv2_b, qkv2, 2048, 2304, 768);

  build_qkv_k<<<(BB*NHEADS*NN)/4, 256, 0, stream>>>(qkv1, qkv2, qk_sc, Qb, Kb, Vtmp);

  vtrans_k<<<dim3(NN/32, DHH/32, 16), 256, 0, stream>>>(Vtmp, Vt);

  attn_mfma_k<<<16*16, 512, 0, stream>>>(Qb, Kb, Vt, AO);

  // out projection + fused gated residual -> d_out (16-wave split-K)
  gemm16_k<3,0><<<192, 1024, 0, stream>>>(
      AO, outt, out_b, AO, outt, out_b,
      modb, x_s1, x_s2, out0, out1, 2, 5, 4096, 768, 768);

  rmsnorm2_k<<<2*BB*TT, 256, 0, stream>>>(out0, n21_w, 6, 7, xm1,
                                          out1, n22_w, 9, 10, xm2, modb);

  // MLP up (dual, GELU, pipelined, swizzled) -> bf16
  gemm_pipe_k<2,1><<<dim3(24, 16, 2), 256, 0, stream>>>(
      xm1, w11t, m1b1, H1, xm2, w21t, m2b1, H2, 2048, 3072, 768);

  // MLP down (dual) + fused final gated add (16-wave split-K)
  gemm16_k<4,1><<<192, 1024, 0, stream>>>(
      H1, w12t, m1b2, H2, w22t, m2b2,
      modb, nullptr, nullptr, out0, out1, 8, 11, 2048, 768, 3072);
}